// Round 1
// baseline (299.716 us; speedup 1.0000x reference)
//
#include <hip/hip_runtime.h>
#include <math.h>

// Problem constants (match reference)
#define BB   16
#define NN_  256
#define NSH  16

__global__ __launch_bounds__(256) void aev_sv_kernel(
    const float* __restrict__ coord,   // [B, N, 3]
    const float* __restrict__ shifts,  // [16]
    const float* __restrict__ eta_p,   // [1]
    const float* __restrict__ rc_p,    // [1]
    float* __restrict__ out)           // d_ij | gs | gv concatenated
{
    const int p = blockIdx.x * blockDim.x + threadIdx.x;   // pair index [0, B*N*N)
    const int NNsq = NN_ * NN_;                             // 65536
    const int b  = p >> 16;
    const int ij = p & (NNsq - 1);
    const int i  = ij >> 8;
    const int j  = ij & (NN_ - 1);

    const float rc  = rc_p[0];
    const float eta = eta_p[0];

    const float* ci = coord + ((size_t)b * NN_ + i) * 3;
    const float* cj = coord + ((size_t)b * NN_ + j) * 3;
    // r_ij = coord[b,j] - coord[b,i]
    const float dx = cj[0] - ci[0];
    const float dy = cj[1] - ci[1];
    const float dz = cj[2] - ci[2];
    const float sq = dx * dx + dy * dy + dz * dz;

    float d, fc;
    if (i == j) {
        d  = rc;      // dmat_fill
        fc = 0.0f;    // masked on diagonal
    } else {
        d  = sqrtf(sq);
        fc = (d < rc) ? (0.5f * cospif(d / rc) + 0.5f) : 0.0f;
    }

    const float inv_d = 1.0f / d;       // diagonal: r=0 -> u=0 (d=rc, safe)
    const float ux = dx * inv_d;
    const float uy = dy * inv_d;
    const float uz = dz * inv_d;

    // Gaussian basis * cutoff
    float gs[NSH];
#pragma unroll
    for (int k = 0; k < NSH; ++k) {
        const float t = d - shifts[k];
        gs[k] = expf(-eta * t * t) * fc;
    }

    // ---- stores ----
    const size_t BNN = (size_t)BB * NNsq;   // 1,048,576

    // d_ij
    out[p] = d;

    // gs: [B,N,N,16] -> 4x float4, 16B-aligned (p*64 bytes)
    float4* gs_out = (float4*)(out + BNN + (size_t)p * NSH);
#pragma unroll
    for (int q = 0; q < 4; ++q)
        gs_out[q] = make_float4(gs[4 * q + 0], gs[4 * q + 1],
                                gs[4 * q + 2], gs[4 * q + 3]);

    // gv: [B,N,N,3,16] -> 12x float4 (p*192 bytes, 16B-aligned)
    float* gv_base = out + BNN + BNN * (size_t)NSH + (size_t)p * 3 * NSH;
    const float u[3] = {ux, uy, uz};
#pragma unroll
    for (int c = 0; c < 3; ++c) {
        float4* gv_out = (float4*)(gv_base + c * NSH);
#pragma unroll
        for (int q = 0; q < 4; ++q)
            gv_out[q] = make_float4(gs[4 * q + 0] * u[c], gs[4 * q + 1] * u[c],
                                    gs[4 * q + 2] * u[c], gs[4 * q + 3] * u[c]);
    }
}

extern "C" void kernel_launch(void* const* d_in, const int* in_sizes, int n_in,
                              void* d_out, int out_size, void* d_ws, size_t ws_size,
                              hipStream_t stream) {
    const float* coord  = (const float*)d_in[0];
    const float* shifts = (const float*)d_in[1];
    const float* eta    = (const float*)d_in[2];
    const float* rc     = (const float*)d_in[3];
    float* out = (float*)d_out;

    const int total = BB * NN_ * NN_;           // 1,048,576 pairs
    const int block = 256;
    const int grid  = total / block;            // 4096
    aev_sv_kernel<<<grid, block, 0, stream>>>(coord, shifts, eta, rc, out);
}

// Round 4
// 263.702 us; speedup vs baseline: 1.1366x; 1.1366x over previous
//
#include <hip/hip_runtime.h>
#include <math.h>

// Problem constants (match reference)
#define BB   16
#define NN_  256
#define NSH  16

// Thread mapping: 4 threads per (b,i,j) pair; thread q of a pair owns
// shifts [4q, 4q+4). All global stores are lane-contiguous full 64B sectors.
__global__ __launch_bounds__(256) void aev_sv_kernel(
    const float* __restrict__ coord,   // [B, N, 3]
    const float* __restrict__ shifts,  // [16]
    const float* __restrict__ eta_p,   // [1]
    const float* __restrict__ rc_p,    // [1]
    float* __restrict__ out)           // d_ij | gs | gv concatenated
{
    const int tid = blockIdx.x * blockDim.x + threadIdx.x;  // [0, 4*B*N*N)
    const int p = tid >> 2;            // pair index [0, B*N*N)
    const int q = tid & 3;             // quad of shifts
    const int b  = p >> 16;
    const int ij = p & 65535;
    const int i  = ij >> 8;
    const int j  = ij & 255;

    const float rc  = rc_p[0];
    const float eta = eta_p[0];

    const float* ci = coord + (b * NN_ + i) * 3;
    const float* cj = coord + (b * NN_ + j) * 3;
    // r_ij = coord[b,j] - coord[b,i]
    const float dx = cj[0] - ci[0];
    const float dy = cj[1] - ci[1];
    const float dz = cj[2] - ci[2];
    const float sq = dx * dx + dy * dy + dz * dz;

    float d, fc;
    if (i == j) {
        d  = rc;      // dmat_fill
        fc = 0.0f;    // masked on diagonal
    } else {
        d  = sqrtf(sq);
        fc = (d < rc) ? (0.5f * cospif(d / rc) + 0.5f) : 0.0f;
    }

    const float inv_d = 1.0f / d;   // diagonal: dx=dy=dz=0 -> u=0, matches ref
    const float ux = dx * inv_d;
    const float uy = dy * inv_d;
    const float uz = dz * inv_d;

    // 4 Gaussians for this thread's quad of shifts
    const float4 sh = ((const float4*)shifts)[q];
    const float neta = -eta;
    const float t0 = d - sh.x, t1 = d - sh.y, t2 = d - sh.z, t3 = d - sh.w;
    const float g0 = expf(neta * t0 * t0) * fc;
    const float g1 = expf(neta * t1 * t1) * fc;
    const float g2 = expf(neta * t2 * t2) * fc;
    const float g3 = expf(neta * t3 * t3) * fc;

    // ---- stores (all lane-contiguous) ----
    constexpr int BNN = BB * NN_ * NN_;               // 1,048,576 (d_ij elems)
    constexpr size_t GS_OFF = (size_t)BNN;            // float offset of gs
    constexpr size_t GV_OFF = GS_OFF + (size_t)BNN * NSH;  // float offset of gv

    // d_ij: one lane per pair (q==0); active lanes write contiguous floats
    if (q == 0) out[p] = d;

    // gs: [B,N,N,16] -> float4 index p*4 + q (consecutive lanes contiguous)
    float4* gs_out = (float4*)(out + GS_OFF);
    gs_out[p * 4 + q] = make_float4(g0, g1, g2, g3);

    // gv: [B,N,N,3,16] -> float4 index p*12 + c*4 + q
    float4* gv_out = (float4*)(out + GV_OFF);
    gv_out[p * 12 + 0 * 4 + q] = make_float4(g0 * ux, g1 * ux, g2 * ux, g3 * ux);
    gv_out[p * 12 + 1 * 4 + q] = make_float4(g0 * uy, g1 * uy, g2 * uy, g3 * uy);
    gv_out[p * 12 + 2 * 4 + q] = make_float4(g0 * uz, g1 * uz, g2 * uz, g3 * uz);
}

extern "C" void kernel_launch(void* const* d_in, const int* in_sizes, int n_in,
                              void* d_out, int out_size, void* d_ws, size_t ws_size,
                              hipStream_t stream) {
    const float* coord  = (const float*)d_in[0];
    const float* shifts = (const float*)d_in[1];
    const float* eta    = (const float*)d_in[2];
    const float* rc     = (const float*)d_in[3];
    float* out = (float*)d_out;

    const int total = BB * NN_ * NN_ * 4;       // 4,194,304 threads
    const int block = 256;
    const int grid  = total / block;            // 16384
    aev_sv_kernel<<<grid, block, 0, stream>>>(coord, shifts, eta, rc, out);
}